// Round 1
// baseline (131.246 us; speedup 1.0000x reference)
//
#include <hip/hip_runtime.h>
#include <hip/hip_bf16.h>

#define D_IN  2048
#define D_OUT 2048
#define M_TOTAL 8192   // B*S = 4*2048

typedef __attribute__((ext_vector_type(4))) float  f32x4;
typedef __attribute__((ext_vector_type(8))) short  short8;   // 8 bf16 for MFMA A/B frags
typedef __attribute__((ext_vector_type(4))) unsigned short u16x4;

typedef const __attribute__((address_space(1))) void gvoid_t;
typedef __attribute__((address_space(3))) void lvoid_t;

__device__ __forceinline__ unsigned short f2bf_rne(float f) {
    unsigned int u = __builtin_bit_cast(unsigned int, f);
    u = (u + 0x7FFFu + ((u >> 16) & 1u));
    return (unsigned short)(u >> 16);
}

// ---------------------------------------------------------------------------
// Kernel 1: per-block partial sums of |w| in fp64 (deterministic, no atomics)
// ---------------------------------------------------------------------------
__global__ __launch_bounds__(256) void absum_kernel(const float* __restrict__ w,
                                                    double* __restrict__ partials) {
    const int n4 = (D_OUT * D_IN) / 4;          // 1,048,576 float4s
    int tid = blockIdx.x * 256 + threadIdx.x;
    int stride = gridDim.x * 256;
    double s = 0.0;
    for (int i = tid; i < n4; i += stride) {
        float4 v = reinterpret_cast<const float4*>(w)[i];
        s += (double)fabsf(v.x) + (double)fabsf(v.y) +
             (double)fabsf(v.z) + (double)fabsf(v.w);
    }
    // wave64 butterfly
    for (int off = 32; off; off >>= 1) s += __shfl_xor(s, off, 64);
    __shared__ double ls[4];
    if ((threadIdx.x & 63) == 0) ls[threadIdx.x >> 6] = s;
    __syncthreads();
    if (threadIdx.x == 0)
        partials[blockIdx.x] = ls[0] + ls[1] + ls[2] + ls[3];
}

// ---------------------------------------------------------------------------
// Kernel 2: reduce 1024 partials -> scale+eps and its reciprocal (fp64)
// ---------------------------------------------------------------------------
__global__ __launch_bounds__(256) void finalize_kernel(const double* __restrict__ partials,
                                                       double* __restrict__ spe) {
    int t = threadIdx.x;
    double s = partials[t] + partials[t + 256] + partials[t + 512] + partials[t + 768];
    for (int off = 32; off; off >>= 1) s += __shfl_xor(s, off, 64);
    __shared__ double ls[4];
    if ((t & 63) == 0) ls[t >> 6] = s;
    __syncthreads();
    if (t == 0) {
        double tot = ls[0] + ls[1] + ls[2] + ls[3];
        double scale = tot / (double)(D_OUT * (double)D_IN);
        double d = scale + 1e-5;
        spe[0] = d;
        spe[1] = 1.0 / d;
    }
}

// ---------------------------------------------------------------------------
// Kernel 3: ternary quantize weight -> bf16 [D_OUT][D_IN]  (B^T layout)
// ---------------------------------------------------------------------------
__global__ __launch_bounds__(256) void quant_kernel(const float* __restrict__ w,
                                                    const double* __restrict__ spe,
                                                    unsigned short* __restrict__ wq) {
    double inv = spe[1];
    int i = blockIdx.x * 256 + threadIdx.x;        // 1M threads, 4 elems each
    float4 v = reinterpret_cast<const float4*>(w)[i];
    u16x4 o;
    #pragma unroll
    for (int j = 0; j < 4; ++j) {
        float wf = (j == 0) ? v.x : (j == 1) ? v.y : (j == 2) ? v.z : v.w;
        double r = rint((double)wf * inv);
        r = fmin(1.0, fmax(-1.0, r));
        float f = (float)r;                         // exactly -1, 0, or 1
        o[j] = (unsigned short)(__builtin_bit_cast(unsigned int, f) >> 16);
    }
    *reinterpret_cast<u16x4*>(&wq[i * 4]) = o;
}

// ---------------------------------------------------------------------------
// Kernel 4: fused LayerNorm (fp32 in) -> bf16 [M][D_IN]
// one block per row; 256 threads x 8 elements
// ---------------------------------------------------------------------------
__global__ __launch_bounds__(256) void ln_kernel(const float* __restrict__ x,
                                                 const float* __restrict__ gamma,
                                                 const float* __restrict__ beta,
                                                 unsigned short* __restrict__ xn) {
    int row = blockIdx.x;
    const float4* xr = reinterpret_cast<const float4*>(x + (size_t)row * D_IN);
    int t = threadIdx.x;
    float4 v0 = xr[t];
    float4 v1 = xr[t + 256];
    float s  = v0.x + v0.y + v0.z + v0.w + v1.x + v1.y + v1.z + v1.w;
    float sq = v0.x*v0.x + v0.y*v0.y + v0.z*v0.z + v0.w*v0.w
             + v1.x*v1.x + v1.y*v1.y + v1.z*v1.z + v1.w*v1.w;
    for (int off = 32; off; off >>= 1) {
        s  += __shfl_xor(s,  off, 64);
        sq += __shfl_xor(sq, off, 64);
    }
    __shared__ float lss[4], lqq[4];
    if ((t & 63) == 0) { lss[t >> 6] = s; lqq[t >> 6] = sq; }
    __syncthreads();
    s  = lss[0] + lss[1] + lss[2] + lss[3];
    sq = lqq[0] + lqq[1] + lqq[2] + lqq[3];
    float mu  = s * (1.0f / D_IN);
    float var = sq * (1.0f / D_IN) - mu * mu;
    float inv = rsqrtf(var + 1e-5f);

    const float4* g4 = reinterpret_cast<const float4*>(gamma);
    const float4* b4 = reinterpret_cast<const float4*>(beta);
    float4 g0 = g4[t], g1 = g4[t + 256];
    float4 b0 = b4[t], b1 = b4[t + 256];

    u16x4 o0, o1;
    o0[0] = f2bf_rne((v0.x - mu) * inv * g0.x + b0.x);
    o0[1] = f2bf_rne((v0.y - mu) * inv * g0.y + b0.y);
    o0[2] = f2bf_rne((v0.z - mu) * inv * g0.z + b0.z);
    o0[3] = f2bf_rne((v0.w - mu) * inv * g0.w + b0.w);
    o1[0] = f2bf_rne((v1.x - mu) * inv * g1.x + b1.x);
    o1[1] = f2bf_rne((v1.y - mu) * inv * g1.y + b1.y);
    o1[2] = f2bf_rne((v1.z - mu) * inv * g1.z + b1.z);
    o1[3] = f2bf_rne((v1.w - mu) * inv * g1.w + b1.w);

    unsigned short* orow = xn + (size_t)row * D_IN;
    *reinterpret_cast<u16x4*>(&orow[t * 4])        = o0;
    *reinterpret_cast<u16x4*>(&orow[1024 + t * 4]) = o1;
}

// ---------------------------------------------------------------------------
// Kernel 5: bf16 MFMA GEMM.  C[m][n] = sum_k A[m][k]*B[n][k] + bias[n]
// A = xn [M][K] bf16, B = wq [N][K] bf16 (B^T layout). 128x128 tile, BK=32.
// 4 waves in 2x2; each wave 64x64 via 4x4 grid of 16x16x32 MFMA.
// ---------------------------------------------------------------------------
#define BM 128
#define BN 128
#define BK 32

__global__ __launch_bounds__(256) void gemm_kernel(const unsigned short* __restrict__ A,
                                                   const unsigned short* __restrict__ B,
                                                   const float* __restrict__ bias,
                                                   float* __restrict__ C) {
    __shared__ unsigned short Al[BM * BK];   // [128][32]
    __shared__ unsigned short Bl[BN * BK];   // [128][32]

    const int tid  = threadIdx.x;
    const int lane = tid & 63;
    const int wave = tid >> 6;
    const int wr   = wave >> 1;          // wave row 0..1
    const int wc   = wave & 1;           // wave col 0..1
    const int bm   = blockIdx.y * BM;
    const int bn   = blockIdx.x * BN;

    f32x4 acc[4][4] = {};

    const int trow = tid >> 2;           // 0..63
    const int tcol = (tid & 3) * 8;      // 0,8,16,24

    const unsigned short* Asrc0 = A + (size_t)(bm + trow)      * D_IN + tcol;
    const unsigned short* Asrc1 = A + (size_t)(bm + 64 + trow) * D_IN + tcol;
    const unsigned short* Bsrc0 = B + (size_t)(bn + trow)      * D_IN + tcol;
    const unsigned short* Bsrc1 = B + (size_t)(bn + 64 + trow) * D_IN + tcol;

    // LDS destinations: linear, lane-stride 16B (global_load_lds requirement)
    unsigned short* Adst0 = &Al[trow * BK + tcol];
    unsigned short* Adst1 = &Al[(64 + trow) * BK + tcol];
    unsigned short* Bdst0 = &Bl[trow * BK + tcol];
    unsigned short* Bdst1 = &Bl[(64 + trow) * BK + tcol];

    const int lr = lane & 15;            // fragment row/col within 16
    const int lk = (lane >> 4) * 8;      // k offset within 32

    for (int k0 = 0; k0 < D_IN; k0 += BK) {
        __builtin_amdgcn_global_load_lds((gvoid_t*)(Asrc0 + k0), (lvoid_t*)Adst0, 16, 0, 0);
        __builtin_amdgcn_global_load_lds((gvoid_t*)(Asrc1 + k0), (lvoid_t*)Adst1, 16, 0, 0);
        __builtin_amdgcn_global_load_lds((gvoid_t*)(Bsrc0 + k0), (lvoid_t*)Bdst0, 16, 0, 0);
        __builtin_amdgcn_global_load_lds((gvoid_t*)(Bsrc1 + k0), (lvoid_t*)Bdst1, 16, 0, 0);
        __syncthreads();

        short8 af[4], bfv[4];
        #pragma unroll
        for (int m = 0; m < 4; ++m)
            af[m] = *reinterpret_cast<const short8*>(&Al[(wr*64 + m*16 + lr) * BK + lk]);
        #pragma unroll
        for (int n = 0; n < 4; ++n)
            bfv[n] = *reinterpret_cast<const short8*>(&Bl[(wc*64 + n*16 + lr) * BK + lk]);
        #pragma unroll
        for (int m = 0; m < 4; ++m)
            #pragma unroll
            for (int n = 0; n < 4; ++n)
                acc[m][n] = __builtin_amdgcn_mfma_f32_16x16x32_bf16(af[m], bfv[n], acc[m][n], 0, 0, 0);
        __syncthreads();
    }

    // Epilogue: C/D layout col=lane&15, row=(lane>>4)*4+r  (m89/m91 verified)
    const int rbase = (lane >> 4) * 4;
    #pragma unroll
    for (int m = 0; m < 4; ++m) {
        #pragma unroll
        for (int n = 0; n < 4; ++n) {
            int r0 = bm + wr*64 + m*16 + rbase;
            int c0 = bn + wc*64 + n*16 + lr;
            float bv = bias[c0];
            #pragma unroll
            for (int r = 0; r < 4; ++r)
                C[(size_t)(r0 + r) * D_OUT + c0] = acc[m][n][r] + bv;
        }
    }
}

// ---------------------------------------------------------------------------
extern "C" void kernel_launch(void* const* d_in, const int* in_sizes, int n_in,
                              void* d_out, int out_size, void* d_ws, size_t ws_size,
                              hipStream_t stream) {
    const float* x     = (const float*)d_in[0];   // [4,2048,2048]
    const float* w     = (const float*)d_in[1];   // [2048,2048]
    const float* bias  = (const float*)d_in[2];   // [2048]
    const float* gamma = (const float*)d_in[3];   // [2048]
    const float* beta  = (const float*)d_in[4];   // [2048]
    float* out = (float*)d_out;

    char* ws = (char*)d_ws;
    double* partials = (double*)ws;                               // 1024 doubles = 8KB
    double* spe      = (double*)(ws + 8192);                      // [0]=scale+eps, [1]=1/(scale+eps)
    unsigned short* wq = (unsigned short*)(ws + 16384);           // 8 MB bf16 [N][K]
    unsigned short* xn = (unsigned short*)(ws + 16384 + 8ull*1024*1024); // 32 MB bf16 [M][K]

    absum_kernel   <<<1024, 256, 0, stream>>>(w, partials);
    finalize_kernel<<<1,    256, 0, stream>>>(partials, spe);
    quant_kernel   <<<4096, 256, 0, stream>>>(w, spe, wq);
    ln_kernel      <<<M_TOTAL, 256, 0, stream>>>(x, gamma, beta, xn);
    gemm_kernel    <<<dim3(D_OUT / BN, M_TOTAL / BM), 256, 0, stream>>>(xn, wq, bias, out);
}

// Round 2
// 96.872 us; speedup vs baseline: 1.3548x; 1.3548x over previous
//
#include <hip/hip_runtime.h>
#include <hip/hip_bf16.h>

#define D_IN  2048
#define D_OUT 2048
#define M_TOTAL 8192   // B*S = 4*2048

typedef __attribute__((ext_vector_type(4))) float  f32x4;
typedef __attribute__((ext_vector_type(8))) short  short8;   // 8 bf16 for MFMA A/B frags
typedef __attribute__((ext_vector_type(4))) unsigned short u16x4;

typedef const __attribute__((address_space(1))) void gvoid_t;
typedef __attribute__((address_space(3))) void lvoid_t;

__device__ __forceinline__ unsigned short f2bf_rne(float f) {
    unsigned int u = __builtin_bit_cast(unsigned int, f);
    u = (u + 0x7FFFu + ((u >> 16) & 1u));
    return (unsigned short)(u >> 16);
}

// ---------------------------------------------------------------------------
// Kernel 1: per-block partial sums of |w| in fp64 (deterministic, no atomics)
// ---------------------------------------------------------------------------
__global__ __launch_bounds__(256) void absum_kernel(const float* __restrict__ w,
                                                    double* __restrict__ partials) {
    const int n4 = (D_OUT * D_IN) / 4;          // 1,048,576 float4s
    int tid = blockIdx.x * 256 + threadIdx.x;
    int stride = gridDim.x * 256;
    double s = 0.0;
    for (int i = tid; i < n4; i += stride) {
        float4 v = reinterpret_cast<const float4*>(w)[i];
        s += (double)fabsf(v.x) + (double)fabsf(v.y) +
             (double)fabsf(v.z) + (double)fabsf(v.w);
    }
    for (int off = 32; off; off >>= 1) s += __shfl_xor(s, off, 64);
    __shared__ double ls[4];
    if ((threadIdx.x & 63) == 0) ls[threadIdx.x >> 6] = s;
    __syncthreads();
    if (threadIdx.x == 0)
        partials[blockIdx.x] = ls[0] + ls[1] + ls[2] + ls[3];
}

// ---------------------------------------------------------------------------
// Kernel 2: reduce 1024 partials -> scale+eps and its reciprocal (fp64)
// ---------------------------------------------------------------------------
__global__ __launch_bounds__(256) void finalize_kernel(const double* __restrict__ partials,
                                                       double* __restrict__ spe) {
    int t = threadIdx.x;
    double s = partials[t] + partials[t + 256] + partials[t + 512] + partials[t + 768];
    for (int off = 32; off; off >>= 1) s += __shfl_xor(s, off, 64);
    __shared__ double ls[4];
    if ((t & 63) == 0) ls[t >> 6] = s;
    __syncthreads();
    if (t == 0) {
        double tot = ls[0] + ls[1] + ls[2] + ls[3];
        double scale = tot / (double)(D_OUT * (double)D_IN);
        double d = scale + 1e-5;
        spe[0] = d;
        spe[1] = 1.0 / d;
    }
}

// ---------------------------------------------------------------------------
// Kernel 3: ternary quantize weight -> bf16 [D_OUT][D_IN]  (B^T layout)
// ---------------------------------------------------------------------------
__global__ __launch_bounds__(256) void quant_kernel(const float* __restrict__ w,
                                                    const double* __restrict__ spe,
                                                    unsigned short* __restrict__ wq) {
    double inv = spe[1];
    int i = blockIdx.x * 256 + threadIdx.x;        // 1M threads, 4 elems each
    float4 v = reinterpret_cast<const float4*>(w)[i];
    u16x4 o;
    #pragma unroll
    for (int j = 0; j < 4; ++j) {
        float wf = (j == 0) ? v.x : (j == 1) ? v.y : (j == 2) ? v.z : v.w;
        double r = rint((double)wf * inv);
        r = fmin(1.0, fmax(-1.0, r));
        float f = (float)r;                         // exactly -1, 0, or 1
        o[j] = (unsigned short)(__builtin_bit_cast(unsigned int, f) >> 16);
    }
    *reinterpret_cast<u16x4*>(&wq[i * 4]) = o;
}

// ---------------------------------------------------------------------------
// Kernel 4: fused LayerNorm (fp32 in) -> bf16 [M][D_IN]
// ---------------------------------------------------------------------------
__global__ __launch_bounds__(256) void ln_kernel(const float* __restrict__ x,
                                                 const float* __restrict__ gamma,
                                                 const float* __restrict__ beta,
                                                 unsigned short* __restrict__ xn) {
    int row = blockIdx.x;
    const float4* xr = reinterpret_cast<const float4*>(x + (size_t)row * D_IN);
    int t = threadIdx.x;
    float4 v0 = xr[t];
    float4 v1 = xr[t + 256];
    float s  = v0.x + v0.y + v0.z + v0.w + v1.x + v1.y + v1.z + v1.w;
    float sq = v0.x*v0.x + v0.y*v0.y + v0.z*v0.z + v0.w*v0.w
             + v1.x*v1.x + v1.y*v1.y + v1.z*v1.z + v1.w*v1.w;
    for (int off = 32; off; off >>= 1) {
        s  += __shfl_xor(s,  off, 64);
        sq += __shfl_xor(sq, off, 64);
    }
    __shared__ float lss[4], lqq[4];
    if ((t & 63) == 0) { lss[t >> 6] = s; lqq[t >> 6] = sq; }
    __syncthreads();
    s  = lss[0] + lss[1] + lss[2] + lss[3];
    sq = lqq[0] + lqq[1] + lqq[2] + lqq[3];
    float mu  = s * (1.0f / D_IN);
    float var = sq * (1.0f / D_IN) - mu * mu;
    float inv = rsqrtf(var + 1e-5f);

    const float4* g4 = reinterpret_cast<const float4*>(gamma);
    const float4* b4 = reinterpret_cast<const float4*>(beta);
    float4 g0 = g4[t], g1 = g4[t + 256];
    float4 b0 = b4[t], b1 = b4[t + 256];

    u16x4 o0, o1;
    o0[0] = f2bf_rne((v0.x - mu) * inv * g0.x + b0.x);
    o0[1] = f2bf_rne((v0.y - mu) * inv * g0.y + b0.y);
    o0[2] = f2bf_rne((v0.z - mu) * inv * g0.z + b0.z);
    o0[3] = f2bf_rne((v0.w - mu) * inv * g0.w + b0.w);
    o1[0] = f2bf_rne((v1.x - mu) * inv * g1.x + b1.x);
    o1[1] = f2bf_rne((v1.y - mu) * inv * g1.y + b1.y);
    o1[2] = f2bf_rne((v1.z - mu) * inv * g1.z + b1.z);
    o1[3] = f2bf_rne((v1.w - mu) * inv * g1.w + b1.w);

    unsigned short* orow = xn + (size_t)row * D_IN;
    *reinterpret_cast<u16x4*>(&orow[t * 4])        = o0;
    *reinterpret_cast<u16x4*>(&orow[1024 + t * 4]) = o1;
}

// ---------------------------------------------------------------------------
// Kernel 5: 256x256-tile 8-wave deep-pipelined bf16 MFMA GEMM (8-phase style)
// C[m][n] = sum_k A[m][k]*B[n][k] + bias[n];  A=[8192][2048] bf16, B=[2048][2048] bf16
//
// LDS per slot (2 slots, 128 KiB total):
//   A: [kh(2)][row(256)][col(32)] bf16 (16 KiB per kh-quantum), B: same at +32KB.
// Swizzle (T2, both-sides): physical 16B-slot = logical slot ^ ((row>>1)&3).
//   Applied at the GLOBAL source during staging (LDS dest stays linear, m173)
//   and at the ds_read address. Reduces 8-way bank conflict to free 2-way.
// Schedule per K-tile T (4 phases, quanta = {A,B}x{kh0,kh1} of later tiles):
//   ph0: read A[m0-3]kh0 + B kh0 (8xb128) | stage A-kh1 of T+1 | bar | 16 MFMA | bar
//   ph1: read A[m4-7]kh0 (4xb128)         | stage B-kh1 of T+1 | bar | 16 MFMA | bar
//   ph2: read A[m0-3]kh1 + B kh1 (8xb128) | stage A-kh0 of T+2 | bar | 16 MFMA | bar
//   ph3: read A[m4-7]kh1 (4xb128)         | stage B-kh0 of T+2 | bar | 16 MFMA |
//        vmcnt(4) (counted, T4) | bar
// Every staged region's last read completes >=1 trailing barrier before the
// stage issue; vmcnt(4) before reading tile T leaves T+1's kh0 (4 loads) in flight.
// ---------------------------------------------------------------------------
#define BM 256
#define BN 256
#define BKT 64
#define NT (D_IN / BKT)        // 32
#define SLOT_BYTES 65536
#define B_OFF 32768
#define KH_BYTES 16384

__device__ __forceinline__ void stage_quantum(const unsigned short* __restrict__ gbase,
                                              int grow0, int kcol0,
                                              char* smem, int ldsbase, int tid) {
    const int lane = tid & 63;
    const int w    = tid >> 6;
    // pre-swizzled global column: slot_p ^ f(row), f(row)=((row>>1)&3)=(lane>>3)&3 here
    const int colx = (((lane & 3) ^ ((lane >> 3) & 3)) << 3);
    #pragma unroll
    for (int j = 0; j < 2; ++j) {
        const int c = w * 2 + j;                    // 1KB chunk id, 0..15
        const int r = c * 16 + (lane >> 2);         // row within 256
        const unsigned short* g = gbase + (size_t)(grow0 + r) * D_IN + (kcol0 + colx);
        char* l = smem + ldsbase + c * 1024 + lane * 16;   // linear: wave-uniform + lane*16
        __builtin_amdgcn_global_load_lds((gvoid_t*)g, (lvoid_t*)l, 16, 0, 0);
    }
}

__device__ __forceinline__ short8 rdfrag(const char* smem, int off) {
    return *reinterpret_cast<const short8*>(smem + off);
}

template<bool S1, bool S2, int VMN>
__device__ __forceinline__ void gemm_body(int T,
        const unsigned short* __restrict__ A, const unsigned short* __restrict__ B,
        int bm, int bn, char* smem, int tid, int aBase, int bBase,
        f32x4 (&acc)[8][4]) {
    const int sb = (T & 1) * SLOT_BYTES;
    const int so = sb ^ SLOT_BYTES;

    // ---- phase 0: (m0-3, kh0) ----
    short8 a0[4], b0[4];
    #pragma unroll
    for (int f = 0; f < 4; ++f) a0[f] = rdfrag(smem, sb + aBase + f * 1024);
    #pragma unroll
    for (int n = 0; n < 4; ++n) b0[n] = rdfrag(smem, sb + bBase + n * 1024);
    if (S1) stage_quantum(A, bm, (T + 1) * BKT + 32, smem, so + KH_BYTES, tid);
    asm volatile("s_barrier" ::: "memory");
    __builtin_amdgcn_s_setprio(1);
    #pragma unroll
    for (int m = 0; m < 4; ++m)
        #pragma unroll
        for (int n = 0; n < 4; ++n)
            acc[m][n] = __builtin_amdgcn_mfma_f32_16x16x32_bf16(a0[m], b0[n], acc[m][n], 0, 0, 0);
    __builtin_amdgcn_s_setprio(0);
    asm volatile("s_barrier" ::: "memory");

    // ---- phase 1: (m4-7, kh0) ----
    short8 a1[4];
    #pragma unroll
    for (int f = 0; f < 4; ++f) a1[f] = rdfrag(smem, sb + aBase + 4096 + f * 1024);
    if (S1) stage_quantum(B, bn, (T + 1) * BKT + 32, smem, so + B_OFF + KH_BYTES, tid);
    asm volatile("s_barrier" ::: "memory");
    __builtin_amdgcn_s_setprio(1);
    #pragma unroll
    for (int m = 0; m < 4; ++m)
        #pragma unroll
        for (int n = 0; n < 4; ++n)
            acc[4 + m][n] = __builtin_amdgcn_mfma_f32_16x16x32_bf16(a1[m], b0[n], acc[4 + m][n], 0, 0, 0);
    __builtin_amdgcn_s_setprio(0);
    asm volatile("s_barrier" ::: "memory");

    // ---- phase 2: (m0-3, kh1) ----
    short8 a2[4], b1[4];
    #pragma unroll
    for (int f = 0; f < 4; ++f) a2[f] = rdfrag(smem, sb + KH_BYTES + aBase + f * 1024);
    #pragma unroll
    for (int n = 0; n < 4; ++n) b1[n] = rdfrag(smem, sb + KH_BYTES + bBase + n * 1024);
    if (S2) stage_quantum(A, bm, (T + 2) * BKT, smem, sb, tid);
    asm volatile("s_barrier" ::: "memory");
    __builtin_amdgcn_s_setprio(1);
    #pragma unroll
    for (int m = 0; m < 4; ++m)
        #pragma unroll
        for (int n = 0; n < 4; ++n)
            acc[m][n] = __builtin_amdgcn_mfma_f32_16x16x32_bf16(a2[m], b1[n], acc[m][n], 0, 0, 0);
    __builtin_amdgcn_s_setprio(0);
    asm volatile("s_barrier" ::: "memory");

    // ---- phase 3: (m4-7, kh1) ----
    short8 a3[4];
    #pragma unroll
    for (int f = 0; f < 4; ++f) a3[f] = rdfrag(smem, sb + KH_BYTES + aBase + 4096 + f * 1024);
    if (S2) stage_quantum(B, bn, (T + 2) * BKT, smem, sb + B_OFF, tid);
    asm volatile("s_barrier" ::: "memory");
    __builtin_amdgcn_s_setprio(1);
    #pragma unroll
    for (int m = 0; m < 4; ++m)
        #pragma unroll
        for (int n = 0; n < 4; ++n)
            acc[4 + m][n] = __builtin_amdgcn_mfma_f32_16x16x32_bf16(a3[m], b1[n], acc[4 + m][n], 0, 0, 0);
    __builtin_amdgcn_s_setprio(0);
    if (VMN == 4) {
        asm volatile("s_waitcnt vmcnt(4)" ::: "memory");
        __builtin_amdgcn_sched_barrier(0);
    } else if (VMN == 0) {
        asm volatile("s_waitcnt vmcnt(0)" ::: "memory");
        __builtin_amdgcn_sched_barrier(0);
    }
    asm volatile("s_barrier" ::: "memory");
}

__global__ __launch_bounds__(512, 2) void gemm256_kernel(const unsigned short* __restrict__ A,
                                                         const unsigned short* __restrict__ B,
                                                         const float* __restrict__ bias,
                                                         float* __restrict__ C) {
    extern __shared__ char smem[];
    const int tid  = threadIdx.x;
    const int lane = tid & 63;
    const int wid  = tid >> 6;
    const int wm   = wid >> 2;           // 0..1
    const int wn   = wid & 3;            // 0..3
    const int bm   = blockIdx.y * BM;
    const int bn   = blockIdx.x * BN;
    const int lr   = lane & 15;
    // swizzled per-lane ds_read base: row=lr, slot = (lane>>4) ^ ((lr>>1)&3)
    const int rdbase = lr * 64 + ((((lane >> 4) ^ ((lr >> 1) & 3))) << 4);
    const int aBase = wm * 8192 + rdbase;
    const int bBase = B_OFF + wn * 4096 + rdbase;

    f32x4 acc[8][4];
    #pragma unroll
    for (int m = 0; m < 8; ++m)
        #pragma unroll
        for (int n = 0; n < 4; ++n)
            acc[m][n] = (f32x4){0.f, 0.f, 0.f, 0.f};

    // prologue: tile0 fully, tile1 kh0; leaves tile1-kh0's 4 loads in flight
    stage_quantum(A, bm, 0,  smem, 0,                          tid);
    stage_quantum(B, bn, 0,  smem, B_OFF,                      tid);
    stage_quantum(A, bm, 32, smem, KH_BYTES,                   tid);
    stage_quantum(B, bn, 32, smem, B_OFF + KH_BYTES,           tid);
    stage_quantum(A, bm, 64, smem, SLOT_BYTES,                 tid);
    stage_quantum(B, bn, 64, smem, SLOT_BYTES + B_OFF,         tid);
    asm volatile("s_waitcnt vmcnt(4)" ::: "memory");
    __builtin_amdgcn_sched_barrier(0);
    asm volatile("s_barrier" ::: "memory");

    for (int T = 0; T < NT - 2; ++T)
        gemm_body<true, true, 4>(T, A, B, bm, bn, smem, tid, aBase, bBase, acc);
    gemm_body<true, false, 0>(NT - 2, A, B, bm, bn, smem, tid, aBase, bBase, acc);
    gemm_body<false, false, -1>(NT - 1, A, B, bm, bn, smem, tid, aBase, bBase, acc);

    // epilogue: C/D layout col=lane&15, row=(lane>>4)*4+i (verified mapping)
    const int rowsub = (lane >> 4) * 4;
    #pragma unroll
    for (int n = 0; n < 4; ++n) {
        const int col = bn + wn * 64 + n * 16 + lr;
        const float bv = bias[col];
        #pragma unroll
        for (int m = 0; m < 8; ++m) {
            const int r0 = bm + wm * 128 + m * 16 + rowsub;
            #pragma unroll
            for (int i = 0; i < 4; ++i)
                C[(size_t)(r0 + i) * D_OUT + col] = acc[m][n][i] + bv;
        }
    }
}

// ---------------------------------------------------------------------------
extern "C" void kernel_launch(void* const* d_in, const int* in_sizes, int n_in,
                              void* d_out, int out_size, void* d_ws, size_t ws_size,
                              hipStream_t stream) {
    const float* x     = (const float*)d_in[0];   // [4,2048,2048]
    const float* w     = (const float*)d_in[1];   // [2048,2048]
    const float* bias  = (const float*)d_in[2];   // [2048]
    const float* gamma = (const float*)d_in[3];   // [2048]
    const float* beta  = (const float*)d_in[4];   // [2048]
    float* out = (float*)d_out;

    char* ws = (char*)d_ws;
    double* partials = (double*)ws;                               // 8KB
    double* spe      = (double*)(ws + 8192);
    unsigned short* wq = (unsigned short*)(ws + 16384);           // 8 MB bf16 [N][K]
    unsigned short* xn = (unsigned short*)(ws + 16384 + 8ull*1024*1024); // 32 MB bf16 [M][K]

    hipFuncSetAttribute(reinterpret_cast<const void*>(gemm256_kernel),
                        hipFuncAttributeMaxDynamicSharedMemorySize, 131072);

    absum_kernel   <<<1024, 256, 0, stream>>>(w, partials);
    finalize_kernel<<<1,    256, 0, stream>>>(partials, spe);
    quant_kernel   <<<4096, 256, 0, stream>>>(w, spe, wq);
    ln_kernel      <<<M_TOTAL, 256, 0, stream>>>(x, gamma, beta, xn);
    gemm256_kernel <<<dim3(D_OUT / BN, M_TOTAL / BM), 512, 131072, stream>>>(xn, wq, bias, out);
}

// Round 3
// 95.932 us; speedup vs baseline: 1.3681x; 1.0098x over previous
//
#include <hip/hip_runtime.h>
#include <hip/hip_bf16.h>

#define D_IN  2048
#define D_OUT 2048
#define M_TOTAL 8192   // B*S = 4*2048

typedef __attribute__((ext_vector_type(4))) float  f32x4;
typedef __attribute__((ext_vector_type(8))) short  short8;   // 8 bf16 for MFMA A/B frags
typedef __attribute__((ext_vector_type(4))) unsigned short u16x4;

typedef const __attribute__((address_space(1))) void gvoid_t;
typedef __attribute__((address_space(3))) void lvoid_t;

__device__ __forceinline__ unsigned short f2bf_rne(float f) {
    unsigned int u = __builtin_bit_cast(unsigned int, f);
    u = (u + 0x7FFFu + ((u >> 16) & 1u));
    return (unsigned short)(u >> 16);
}

// ---------------------------------------------------------------------------
// Kernel 1: per-block partial sums of |w| in fp64 (deterministic, no atomics)
// ---------------------------------------------------------------------------
__global__ __launch_bounds__(256) void absum_kernel(const float* __restrict__ w,
                                                    double* __restrict__ partials) {
    const int n4 = (D_OUT * D_IN) / 4;          // 1,048,576 float4s
    int tid = blockIdx.x * 256 + threadIdx.x;
    int stride = gridDim.x * 256;
    double s = 0.0;
    for (int i = tid; i < n4; i += stride) {
        float4 v = reinterpret_cast<const float4*>(w)[i];
        s += (double)fabsf(v.x) + (double)fabsf(v.y) +
             (double)fabsf(v.z) + (double)fabsf(v.w);
    }
    for (int off = 32; off; off >>= 1) s += __shfl_xor(s, off, 64);
    __shared__ double ls[4];
    if ((threadIdx.x & 63) == 0) ls[threadIdx.x >> 6] = s;
    __syncthreads();
    if (threadIdx.x == 0)
        partials[blockIdx.x] = ls[0] + ls[1] + ls[2] + ls[3];
}

// ---------------------------------------------------------------------------
// Kernel 2: ternary quantize -> bf16 [D_OUT][D_IN]; finalize folded in
// (every block reduces the 1024 partials identically -> deterministic)
// ---------------------------------------------------------------------------
__global__ __launch_bounds__(256) void quant_kernel(const float* __restrict__ w,
                                                    const double* __restrict__ partials,
                                                    unsigned short* __restrict__ wq) {
    int t = threadIdx.x;
    double s = partials[t] + partials[t + 256] + partials[t + 512] + partials[t + 768];
    for (int off = 32; off; off >>= 1) s += __shfl_xor(s, off, 64);
    __shared__ double ls[4];
    if ((t & 63) == 0) ls[t >> 6] = s;
    __syncthreads();
    double tot = ls[0] + ls[1] + ls[2] + ls[3];
    double inv = 1.0 / (tot / 4194304.0 + 1e-5);

    int i = blockIdx.x * 256 + t;                  // 1M threads, 4 elems each
    float4 v = reinterpret_cast<const float4*>(w)[i];
    u16x4 o;
    #pragma unroll
    for (int j = 0; j < 4; ++j) {
        float wf = (j == 0) ? v.x : (j == 1) ? v.y : (j == 2) ? v.z : v.w;
        double r = rint((double)wf * inv);
        r = fmin(1.0, fmax(-1.0, r));
        float f = (float)r;                         // exactly -1, 0, or 1
        o[j] = (unsigned short)(__builtin_bit_cast(unsigned int, f) >> 16);
    }
    *reinterpret_cast<u16x4*>(&wq[i * 4]) = o;
}

// ---------------------------------------------------------------------------
// Kernel 3: fused LayerNorm (fp32 in) -> bf16 [M][D_IN]
// ---------------------------------------------------------------------------
__global__ __launch_bounds__(256) void ln_kernel(const float* __restrict__ x,
                                                 const float* __restrict__ gamma,
                                                 const float* __restrict__ beta,
                                                 unsigned short* __restrict__ xn) {
    int row = blockIdx.x;
    const float4* xr = reinterpret_cast<const float4*>(x + (size_t)row * D_IN);
    int t = threadIdx.x;
    float4 v0 = xr[t];
    float4 v1 = xr[t + 256];
    float s  = v0.x + v0.y + v0.z + v0.w + v1.x + v1.y + v1.z + v1.w;
    float sq = v0.x*v0.x + v0.y*v0.y + v0.z*v0.z + v0.w*v0.w
             + v1.x*v1.x + v1.y*v1.y + v1.z*v1.z + v1.w*v1.w;
    for (int off = 32; off; off >>= 1) {
        s  += __shfl_xor(s,  off, 64);
        sq += __shfl_xor(sq, off, 64);
    }
    __shared__ float lss[4], lqq[4];
    if ((t & 63) == 0) { lss[t >> 6] = s; lqq[t >> 6] = sq; }
    __syncthreads();
    s  = lss[0] + lss[1] + lss[2] + lss[3];
    sq = lqq[0] + lqq[1] + lqq[2] + lqq[3];
    float mu  = s * (1.0f / D_IN);
    float var = sq * (1.0f / D_IN) - mu * mu;
    float inv = rsqrtf(var + 1e-5f);

    const float4* g4 = reinterpret_cast<const float4*>(gamma);
    const float4* b4 = reinterpret_cast<const float4*>(beta);
    float4 g0 = g4[t], g1 = g4[t + 256];
    float4 b0 = b4[t], b1 = b4[t + 256];

    u16x4 o0, o1;
    o0[0] = f2bf_rne((v0.x - mu) * inv * g0.x + b0.x);
    o0[1] = f2bf_rne((v0.y - mu) * inv * g0.y + b0.y);
    o0[2] = f2bf_rne((v0.z - mu) * inv * g0.z + b0.z);
    o0[3] = f2bf_rne((v0.w - mu) * inv * g0.w + b0.w);
    o1[0] = f2bf_rne((v1.x - mu) * inv * g1.x + b1.x);
    o1[1] = f2bf_rne((v1.y - mu) * inv * g1.y + b1.y);
    o1[2] = f2bf_rne((v1.z - mu) * inv * g1.z + b1.z);
    o1[3] = f2bf_rne((v1.w - mu) * inv * g1.w + b1.w);

    unsigned short* orow = xn + (size_t)row * D_IN;
    *reinterpret_cast<u16x4*>(&orow[t * 4])        = o0;
    *reinterpret_cast<u16x4*>(&orow[1024 + t * 4]) = o1;
}

// ---------------------------------------------------------------------------
// Kernel 4: 256x256-tile 8-wave deep-pipelined bf16 MFMA GEMM
// Same schedule as R1 (verified race-free) + sched_barrier(0) pinning of the
// MFMA clusters (rule #18: "memory" clobber does NOT order register-only
// MFMAs; without the fence the compiler can hoist them above the barrier and
// collapse the phase interleave) + XCD-aware block swizzle + LDS-repack
// epilogue with dwordx4 stores.
// ---------------------------------------------------------------------------
#define BM 256
#define BN 256
#define BKT 64
#define NT (D_IN / BKT)        // 32
#define SLOT_BYTES 65536
#define B_OFF 32768
#define KH_BYTES 16384

__device__ __forceinline__ void stage_quantum(const unsigned short* __restrict__ gbase,
                                              int grow0, int kcol0,
                                              char* smem, int ldsbase, int tid) {
    const int lane = tid & 63;
    const int w    = tid >> 6;
    // pre-swizzled global column: slot_p ^ f(row), f(row)=((row>>1)&3)=(lane>>3)&3 here
    const int colx = (((lane & 3) ^ ((lane >> 3) & 3)) << 3);
    #pragma unroll
    for (int j = 0; j < 2; ++j) {
        const int c = w * 2 + j;                    // 1KB chunk id, 0..15
        const int r = c * 16 + (lane >> 2);         // row within 256
        const unsigned short* g = gbase + (size_t)(grow0 + r) * D_IN + (kcol0 + colx);
        char* l = smem + ldsbase + c * 1024 + lane * 16;   // linear: wave-uniform + lane*16
        __builtin_amdgcn_global_load_lds((gvoid_t*)g, (lvoid_t*)l, 16, 0, 0);
    }
}

__device__ __forceinline__ short8 rdfrag(const char* smem, int off) {
    return *reinterpret_cast<const short8*>(smem + off);
}

#define MFMA_CLUSTER(ACCROW, AFR, BFR)                                          \
    asm volatile("s_barrier" ::: "memory");                                     \
    __builtin_amdgcn_sched_barrier(0);                                          \
    __builtin_amdgcn_s_setprio(1);                                              \
    _Pragma("unroll")                                                           \
    for (int m = 0; m < 4; ++m)                                                 \
        _Pragma("unroll")                                                       \
        for (int n = 0; n < 4; ++n)                                             \
            acc[ACCROW + m][n] = __builtin_amdgcn_mfma_f32_16x16x32_bf16(       \
                AFR[m], BFR[n], acc[ACCROW + m][n], 0, 0, 0);                   \
    __builtin_amdgcn_s_setprio(0);                                              \
    __builtin_amdgcn_sched_barrier(0);                                          \
    asm volatile("s_barrier" ::: "memory");

template<bool S1, bool S2, int VMN>
__device__ __forceinline__ void gemm_body(int T,
        const unsigned short* __restrict__ A, const unsigned short* __restrict__ B,
        int bm, int bn, char* smem, int tid, int aBase, int bBase,
        f32x4 (&acc)[8][4]) {
    const int sb = (T & 1) * SLOT_BYTES;
    const int so = sb ^ SLOT_BYTES;

    // ---- phase 0: (m0-3, kh0) ----
    short8 a0[4], b0[4];
    #pragma unroll
    for (int f = 0; f < 4; ++f) a0[f] = rdfrag(smem, sb + aBase + f * 1024);
    #pragma unroll
    for (int n = 0; n < 4; ++n) b0[n] = rdfrag(smem, sb + bBase + n * 1024);
    if (S1) stage_quantum(A, bm, (T + 1) * BKT + 32, smem, so + KH_BYTES, tid);
    MFMA_CLUSTER(0, a0, b0)

    // ---- phase 1: (m4-7, kh0) ----
    short8 a1[4];
    #pragma unroll
    for (int f = 0; f < 4; ++f) a1[f] = rdfrag(smem, sb + aBase + 4096 + f * 1024);
    if (S1) stage_quantum(B, bn, (T + 1) * BKT + 32, smem, so + B_OFF + KH_BYTES, tid);
    MFMA_CLUSTER(4, a1, b0)

    // ---- phase 2: (m0-3, kh1) ----
    short8 a2[4], b1[4];
    #pragma unroll
    for (int f = 0; f < 4; ++f) a2[f] = rdfrag(smem, sb + KH_BYTES + aBase + f * 1024);
    #pragma unroll
    for (int n = 0; n < 4; ++n) b1[n] = rdfrag(smem, sb + KH_BYTES + bBase + n * 1024);
    if (S2) stage_quantum(A, bm, (T + 2) * BKT, smem, sb, tid);
    MFMA_CLUSTER(0, a2, b1)

    // ---- phase 3: (m4-7, kh1) ----
    short8 a3[4];
    #pragma unroll
    for (int f = 0; f < 4; ++f) a3[f] = rdfrag(smem, sb + KH_BYTES + aBase + 4096 + f * 1024);
    if (S2) stage_quantum(B, bn, (T + 2) * BKT, smem, sb + B_OFF, tid);
    // last phase: MFMA cluster, then counted vmcnt before the trailing barrier
    asm volatile("s_barrier" ::: "memory");
    __builtin_amdgcn_sched_barrier(0);
    __builtin_amdgcn_s_setprio(1);
    #pragma unroll
    for (int m = 0; m < 4; ++m)
        #pragma unroll
        for (int n = 0; n < 4; ++n)
            acc[4 + m][n] = __builtin_amdgcn_mfma_f32_16x16x32_bf16(a3[m], b1[n], acc[4 + m][n], 0, 0, 0);
    __builtin_amdgcn_s_setprio(0);
    __builtin_amdgcn_sched_barrier(0);
    if (VMN == 4) {
        asm volatile("s_waitcnt vmcnt(4)" ::: "memory");
        __builtin_amdgcn_sched_barrier(0);
    } else if (VMN == 0) {
        asm volatile("s_waitcnt vmcnt(0)" ::: "memory");
        __builtin_amdgcn_sched_barrier(0);
    }
    asm volatile("s_barrier" ::: "memory");
}

__global__ __launch_bounds__(512, 2) void gemm256_kernel(const unsigned short* __restrict__ A,
                                                         const unsigned short* __restrict__ B,
                                                         const float* __restrict__ bias,
                                                         float* __restrict__ C) {
    extern __shared__ char smem[];
    const int tid  = threadIdx.x;
    const int lane = tid & 63;
    const int wid  = tid >> 6;
    const int wm   = wid >> 2;           // 0..1
    const int wn   = wid & 3;            // 0..3

    // XCD-aware bijective swizzle (grid=256, 256%8==0): each XCD owns 4
    // contiguous M-panels (4MB A in its private L2)
    const int orig = blockIdx.y * gridDim.x + blockIdx.x;   // 0..255
    const int swz  = (orig & 7) * 32 + (orig >> 3);
    const int bm   = (swz >> 3) * BM;
    const int bn   = (swz & 7) * BN;

    const int lr   = lane & 15;
    // swizzled per-lane ds_read base: row=lr, slot = (lane>>4) ^ ((lr>>1)&3)
    const int rdbase = lr * 64 + ((((lane >> 4) ^ ((lr >> 1) & 3))) << 4);
    const int aBase = wm * 8192 + rdbase;
    const int bBase = B_OFF + wn * 4096 + rdbase;

    f32x4 acc[8][4];
    #pragma unroll
    for (int m = 0; m < 8; ++m)
        #pragma unroll
        for (int n = 0; n < 4; ++n)
            acc[m][n] = (f32x4){0.f, 0.f, 0.f, 0.f};

    // prologue: tile0 fully, tile1 kh0; leaves tile1-kh0's 4 loads in flight
    stage_quantum(A, bm, 0,  smem, 0,                          tid);
    stage_quantum(B, bn, 0,  smem, B_OFF,                      tid);
    stage_quantum(A, bm, 32, smem, KH_BYTES,                   tid);
    stage_quantum(B, bn, 32, smem, B_OFF + KH_BYTES,           tid);
    stage_quantum(A, bm, 64, smem, SLOT_BYTES,                 tid);
    stage_quantum(B, bn, 64, smem, SLOT_BYTES + B_OFF,         tid);
    asm volatile("s_waitcnt vmcnt(4)" ::: "memory");
    __builtin_amdgcn_sched_barrier(0);
    asm volatile("s_barrier" ::: "memory");

    for (int T = 0; T < NT - 2; ++T)
        gemm_body<true, true, 4>(T, A, B, bm, bn, smem, tid, aBase, bBase, acc);
    gemm_body<true, false, 0>(NT - 2, A, B, bm, bn, smem, tid, aBase, bBase, acc);
    gemm_body<false, false, -1>(NT - 1, A, B, bm, bn, smem, tid, aBase, bBase, acc);

    // ---- epilogue: per-wave LDS repack -> dwordx4 stores (256B segments) ----
    // All K-loop LDS reads drained before the final barrier; per-wave private
    // regions, so no cross-wave sync needed.
    const int EST = 272;                       // row stride bytes (68 dwords, anti-conflict pad)
    char* eb = smem + wid * (16 * EST);        // 4352 B per wave
    const int C0 = bn + wn * 64;
    const int R0 = bm + wm * 128;
    const int rowsub = (lane >> 4) * 4;
    float bv[4];
    #pragma unroll
    for (int n = 0; n < 4; ++n) bv[n] = bias[C0 + n * 16 + lr];

    #pragma unroll
    for (int m = 0; m < 8; ++m) {
        #pragma unroll
        for (int n = 0; n < 4; ++n)
            #pragma unroll
            for (int i = 0; i < 4; ++i)
                *reinterpret_cast<float*>(eb + (rowsub + i) * EST + (n * 16 + lr) * 4)
                    = acc[m][n][i] + bv[n];
        #pragma unroll
        for (int q = 0; q < 4; ++q) {
            const int row = (lane >> 4) + q * 4;
            f32x4 v = *reinterpret_cast<const f32x4*>(eb + row * EST + lr * 16);
            *reinterpret_cast<f32x4*>(&C[(size_t)(R0 + m * 16 + row) * D_OUT + C0 + lr * 4]) = v;
        }
    }
}

// ---------------------------------------------------------------------------
extern "C" void kernel_launch(void* const* d_in, const int* in_sizes, int n_in,
                              void* d_out, int out_size, void* d_ws, size_t ws_size,
                              hipStream_t stream) {
    const float* x     = (const float*)d_in[0];   // [4,2048,2048]
    const float* w     = (const float*)d_in[1];   // [2048,2048]
    const float* bias  = (const float*)d_in[2];   // [2048]
    const float* gamma = (const float*)d_in[3];   // [2048]
    const float* beta  = (const float*)d_in[4];   // [2048]
    float* out = (float*)d_out;

    char* ws = (char*)d_ws;
    double* partials = (double*)ws;                               // 8KB
    unsigned short* wq = (unsigned short*)(ws + 16384);           // 8 MB bf16 [N][K]
    unsigned short* xn = (unsigned short*)(ws + 16384 + 8ull*1024*1024); // 32 MB bf16 [M][K]

    hipFuncSetAttribute(reinterpret_cast<const void*>(gemm256_kernel),
                        hipFuncAttributeMaxDynamicSharedMemorySize, 131072);

    absum_kernel   <<<1024, 256, 0, stream>>>(w, partials);
    quant_kernel   <<<4096, 256, 0, stream>>>(w, partials, wq);
    ln_kernel      <<<M_TOTAL, 256, 0, stream>>>(x, gamma, beta, xn);
    gemm256_kernel <<<dim3(D_OUT / BN, M_TOTAL / BM), 512, 131072, stream>>>(xn, wq, bias, out);
}